// Round 1
// baseline (2533.520 us; speedup 1.0000x reference)
//
#include <hip/hip_runtime.h>
#include <hip/hip_bf16.h>

#define U16 unsigned short

typedef __attribute__((ext_vector_type(8))) short bf16x8;
typedef __attribute__((ext_vector_type(4))) float f32x4;

__device__ __forceinline__ float bf2f(U16 h) {
  union { unsigned int u; float f; } v; v.u = ((unsigned int)h) << 16; return v.f;
}
__device__ __forceinline__ U16 f2bf(float f) {
  union { float f; unsigned int u; } v; v.f = f;
  unsigned int u = v.u;
  u = (u + 0x7FFFu + ((u >> 16) & 1u)) >> 16;
  return (U16)u;
}
__device__ __forceinline__ float sigm(float x) { return 1.f / (1.f + __expf(-x)); }
__device__ __forceinline__ float tanh_f(float x) {
  x = fminf(10.f, fmaxf(-10.f, x));
  float e = __expf(2.f * x);
  return (e - 1.f) / (e + 1.f);
}

// ---------------- prep kernels ----------------
__global__ void cast_bf16_k(const float* __restrict__ src, U16* __restrict__ dst, int n4) {
  int i = blockIdx.x * blockDim.x + threadIdx.x;
  if (i >= n4) return;
  float4 v = ((const float4*)src)[i];
  uint2 o;
  o.x = (unsigned)f2bf(v.x) | ((unsigned)f2bf(v.y) << 16);
  o.y = (unsigned)f2bf(v.z) | ((unsigned)f2bf(v.w) << 16);
  ((uint2*)dst)[i] = o;
}

__global__ void bias_comb_k(const float* __restrict__ a, const float* __restrict__ b,
                            const float* __restrict__ c, const float* __restrict__ d,
                            float* __restrict__ o1, float* __restrict__ o2) {
  int i = blockIdx.x * blockDim.x + threadIdx.x;
  if (i < 1024) { o1[i] = a[i] + b[i]; o2[i] = c[i] + d[i]; }
}

// ---------------- GEMM: C[M,N] = A[M,K] * B[N,K]^T ----------------
// A fp32 (converted inline) or bf16; C bf16 or fp32(+bias). Frag-linear LDS.
template<bool AF32, bool CF32>
__global__ __launch_bounds__(256) void gemm_bt(
    const void* __restrict__ Av, const U16* __restrict__ Bw,
    void* __restrict__ Cv, int M, int N, int K, const float* __restrict__ bias)
{
  __shared__ __attribute__((aligned(16))) U16 As[8][64][8];
  __shared__ __attribute__((aligned(16))) U16 Bs[8][64][8];
  const int tid = threadIdx.x;
  const int lane = tid & 63, wave = tid >> 6;
  const int wm = wave >> 1, wn = wave & 1;
  const long row0 = (long)blockIdx.y * 128;
  const long col0 = (long)blockIdx.x * 128;

  f32x4 zero = {0.f, 0.f, 0.f, 0.f};
  f32x4 acc[4][4];
#pragma unroll
  for (int mi = 0; mi < 4; ++mi)
#pragma unroll
    for (int ni = 0; ni < 4; ++ni) acc[mi][ni] = zero;

  for (int k0 = 0; k0 < K; k0 += 32) {
    __syncthreads();
    if constexpr (AF32) {
      const float* A = (const float*)Av;
#pragma unroll
      for (int i = 0; i < 4; ++i) {
        int ch = i * 256 + tid;
        int r = ch >> 3, cc = ch & 7;
        const float4 v = *(const float4*)(A + (row0 + r) * (long)K + k0 + cc * 4);
        uint2 o;
        o.x = (unsigned)f2bf(v.x) | ((unsigned)f2bf(v.y) << 16);
        o.y = (unsigned)f2bf(v.z) | ((unsigned)f2bf(v.w) << 16);
        *(uint2*)&As[r >> 4][(cc >> 1) * 16 + (r & 15)][(cc & 1) * 4] = o;
      }
    } else {
      const U16* A = (const U16*)Av;
#pragma unroll
      for (int i = 0; i < 2; ++i) {
        int ch = i * 256 + tid;
        int r = ch >> 2, cc = ch & 3;
        uint4 v = *(const uint4*)(A + (row0 + r) * (long)K + k0 + cc * 8);
        *(uint4*)&As[r >> 4][cc * 16 + (r & 15)][0] = v;
      }
    }
#pragma unroll
    for (int i = 0; i < 2; ++i) {
      int ch = i * 256 + tid;
      int r = ch >> 2, cc = ch & 3;
      uint4 v = *(const uint4*)(Bw + (col0 + r) * (long)K + k0 + cc * 8);
      *(uint4*)&Bs[r >> 4][cc * 16 + (r & 15)][0] = v;
    }
    __syncthreads();
    bf16x8 af[4], bfr[4];
#pragma unroll
    for (int mi = 0; mi < 4; ++mi) af[mi] = *(const bf16x8*)&As[wm * 4 + mi][lane][0];
#pragma unroll
    for (int ni = 0; ni < 4; ++ni) bfr[ni] = *(const bf16x8*)&Bs[wn * 4 + ni][lane][0];
#pragma unroll
    for (int mi = 0; mi < 4; ++mi)
#pragma unroll
      for (int ni = 0; ni < 4; ++ni)
        acc[mi][ni] = __builtin_amdgcn_mfma_f32_16x16x32_bf16(af[mi], bfr[ni], acc[mi][ni], 0, 0, 0);
  }

  const int qa = lane >> 4, ca = lane & 15;
#pragma unroll
  for (int mi = 0; mi < 4; ++mi)
#pragma unroll
    for (int ni = 0; ni < 4; ++ni) {
      long col = col0 + wn * 64 + ni * 16 + ca;
      float bv = 0.f;
      if constexpr (CF32) bv = bias[col];
#pragma unroll
      for (int rr = 0; rr < 4; ++rr) {
        long row = row0 + wm * 64 + mi * 16 + qa * 4 + rr;
        float v = acc[mi][ni][rr];
        if constexpr (CF32) ((float*)Cv)[row * N + col] = v + bv;
        else ((U16*)Cv)[row * N + col] = f2bf(v);
      }
    }
}

// ---------------- bidirectional LSTM scan ----------------
// wg = 256 threads (4 waves) x 64 batch rows x 1 direction. Wave w owns rows
// [w*16, w*16+16). Gates for unit-tile u computed as 4 MFMA tiles at N-offsets
// {u,u+256,u+512,u+768}: identical lane mapping -> lane-local cell update; c in
// 64 VGPRs. h round-trips via frag-linear LDS (per-wave private slice).
__global__ __launch_bounds__(256) void lstm_scan(
    const U16* __restrict__ G, const U16* __restrict__ WhhF,
    const U16* __restrict__ WhhB, const float* __restrict__ biasF,
    const float* __restrict__ biasB, U16* __restrict__ flat)
{
  __shared__ __attribute__((aligned(16))) U16 hbuf[4][8][64][8];  // [mtile][kk][lane][j] 32KB
  __shared__ __attribute__((aligned(16))) U16 Bsl[4][8][64][8];   // [gate][kk][lane][j] 32KB
  const int tid = threadIdx.x;
  const int lane = tid & 63, wave = tid >> 6;
  const int qa = lane >> 4, ca = lane & 15;
  const int dir = blockIdx.y;
  const int row0 = blockIdx.x * 64;
  const U16* Whh = dir ? WhhB : WhhF;
  const float* bias = dir ? biasB : biasF;
  const U16* Gd = G + (size_t)dir * (size_t)67108864;  // [65536][1024] per dir

  uint4 z4 = make_uint4(0, 0, 0, 0);
  for (int i = tid; i < 2048; i += 256) ((uint4*)hbuf)[i] = z4;  // h0 = 0
  __syncthreads();

  float cst[16][4];
#pragma unroll
  for (int u = 0; u < 16; ++u)
#pragma unroll
    for (int r = 0; r < 4; ++r) cst[u][r] = 0.f;

  for (int s = 0; s < 4; ++s) {
    const int t = dir ? (3 - s) : s;
    bf16x8 af[8];  // this wave's h rows x full K=256 (private: written by same wave)
#pragma unroll
    for (int kk = 0; kk < 8; ++kk) af[kk] = *(const bf16x8*)&hbuf[wave][kk][lane][0];

#pragma unroll
    for (int u = 0; u < 16; ++u) {
      __syncthreads();  // Bsl consumed by previous iteration
      // stage Whh rows {g*256+u*16 .. +15} for all 4 gates, frag-linear
#pragma unroll
      for (int i = 0; i < 8; ++i) {
        int ch = i * 256 + tid;       // 2048 chunks of 8 bf16
        int g = ch >> 9, rem = ch & 511;
        int r = rem >> 5, cc = rem & 31;
        uint4 v = *(const uint4*)(Whh + ((size_t)(g * 256 + u * 16 + r) * 256 + cc * 8));
        *(uint4*)&Bsl[g][cc >> 2][(cc & 3) * 16 + r][0] = v;
      }
      __syncthreads();

      f32x4 acc[4];
#pragma unroll
      for (int g = 0; g < 4; ++g) { f32x4 z = {0.f, 0.f, 0.f, 0.f}; acc[g] = z; }
#pragma unroll
      for (int kk = 0; kk < 8; ++kk)
#pragma unroll
        for (int g = 0; g < 4; ++g)
          acc[g] = __builtin_amdgcn_mfma_f32_16x16x32_bf16(
              af[kk], *(const bf16x8*)&Bsl[g][kk][lane][0], acc[g], 0, 0, 0);

      const int unit = u * 16 + ca;
      const float b0 = bias[unit], b1 = bias[256 + unit], b2 = bias[512 + unit], b3 = bias[768 + unit];
#pragma unroll
      for (int r = 0; r < 4; ++r) {
        int lr = wave * 16 + qa * 4 + r;  // local row 0..63
        size_t grow = ((size_t)(row0 + lr) * 4 + t) * 1024;
        float gi = acc[0][r] + b0 + bf2f(Gd[grow + unit]);
        float gf = acc[1][r] + b1 + bf2f(Gd[grow + 256 + unit]);
        float gg = acc[2][r] + b2 + bf2f(Gd[grow + 512 + unit]);
        float go = acc[3][r] + b3 + bf2f(Gd[grow + 768 + unit]);
        float c = sigm(gf) * cst[u][r] + sigm(gi) * tanh_f(gg);
        cst[u][r] = c;
        float h = sigm(go) * tanh_f(c);
        U16 hb = f2bf(h);
        // h -> A-frag layout for next step (k = unit)
        hbuf[wave][u >> 1][((u & 1) * 2 + (ca >> 3)) * 16 + qa * 4 + r][ca & 7] = hb;
        flat[(size_t)(row0 + lr) * 2048 + t * 512 + dir * 256 + unit] = hb;
      }
    }
  }
}

// ---------------- LayerNorm + exact GELU + residual ----------------
__global__ __launch_bounds__(256) void ln_gelu_res(
    const float* __restrict__ y, const float* __restrict__ x,
    const float* __restrict__ lg, const float* __restrict__ lb,
    float* __restrict__ out)
{
  const int row = blockIdx.x, tid = threadIdx.x;
  const float4* yr = (const float4*)(y + (size_t)row * 4096);
  const float4* xr = (const float4*)(x + (size_t)row * 4096);
  float4* outr = (float4*)(out + (size_t)row * 4096);
  const float4* g4 = (const float4*)lg;
  const float4* b4 = (const float4*)lb;
  float4 v[4];
  float s1 = 0.f, s2 = 0.f;
#pragma unroll
  for (int j = 0; j < 4; ++j) {
    float4 t = yr[j * 256 + tid];
    v[j] = t;
    s1 += t.x + t.y + t.z + t.w;
    s2 += t.x * t.x + t.y * t.y + t.z * t.z + t.w * t.w;
  }
#pragma unroll
  for (int off = 32; off > 0; off >>= 1) {
    s1 += __shfl_down(s1, off);
    s2 += __shfl_down(s2, off);
  }
  __shared__ float red[8];
  const int wave = tid >> 6, lane = tid & 63;
  if (lane == 0) { red[wave] = s1; red[4 + wave] = s2; }
  __syncthreads();
  s1 = red[0] + red[1] + red[2] + red[3];
  s2 = red[4] + red[5] + red[6] + red[7];
  const float mu = s1 * (1.f / 4096.f);
  const float rstd = rsqrtf(s2 * (1.f / 4096.f) - mu * mu + 1e-5f);
  const float inv_sqrt2 = 0.70710678118654752f;
#pragma unroll
  for (int j = 0; j < 4; ++j) {
    float4 gg = g4[j * 256 + tid], bb = b4[j * 256 + tid], xx = xr[j * 256 + tid];
    float4 o;
    float tval;
    tval = (v[j].x - mu) * rstd * gg.x + bb.x; o.x = xx.x + 0.5f * tval * (1.f + erff(tval * inv_sqrt2));
    tval = (v[j].y - mu) * rstd * gg.y + bb.y; o.y = xx.y + 0.5f * tval * (1.f + erff(tval * inv_sqrt2));
    tval = (v[j].z - mu) * rstd * gg.z + bb.z; o.z = xx.z + 0.5f * tval * (1.f + erff(tval * inv_sqrt2));
    tval = (v[j].w - mu) * rstd * gg.w + bb.w; o.w = xx.w + 0.5f * tval * (1.f + erff(tval * inv_sqrt2));
    outr[j * 256 + tid] = o;
  }
}

// ---------------- host ----------------
extern "C" void kernel_launch(void* const* d_in, const int* in_sizes, int n_in,
                              void* d_out, int out_size, void* d_ws, size_t ws_size,
                              hipStream_t stream) {
  const float* x      = (const float*)d_in[0];
  const float* Wih_f  = (const float*)d_in[1];
  const float* Whh_f  = (const float*)d_in[2];
  const float* bih_f  = (const float*)d_in[3];
  const float* bhh_f  = (const float*)d_in[4];
  const float* Wih_b  = (const float*)d_in[5];
  const float* Whh_b  = (const float*)d_in[6];
  const float* bih_b  = (const float*)d_in[7];
  const float* bhh_b  = (const float*)d_in[8];
  const float* proj_W = (const float*)d_in[9];
  const float* proj_b = (const float*)d_in[10];
  const float* ln_g   = (const float*)d_in[11];
  const float* ln_b   = (const float*)d_in[12];
  float* out = (float*)d_out;

  char* ws = (char*)d_ws;
  // layout (bytes):
  //   [0, 268435456)        G bf16 [2][65536][1024]  -- later reused as y fp32 [16384][4096]
  //   [268435456, 335544320) flat bf16 [16384][2048]
  //   then bf16 weights + combined biases (~21 MB)
  U16*  G    = (U16*)(ws);
  float* y   = (float*)(ws);                       // overlaps G (G dead after scan)
  U16*  flat = (U16*)(ws + 268435456);
  U16*  WihF = (U16*)(ws + 335544320);
  U16*  WihB = WihF + 1048576;
  U16*  WhhFb = WihB + 1048576;
  U16*  WhhBb = WhhFb + 262144;
  U16*  PW   = WhhBb + 262144;
  float* biasF = (float*)(PW + 8388608);
  float* biasB = biasF + 1024;

  // prep: bf16 casts + combined biases
  cast_bf16_k<<<1024, 256, 0, stream>>>(Wih_f, WihF, 262144);
  cast_bf16_k<<<1024, 256, 0, stream>>>(Wih_b, WihB, 262144);
  cast_bf16_k<<<256, 256, 0, stream>>>(Whh_f, WhhFb, 65536);
  cast_bf16_k<<<256, 256, 0, stream>>>(Whh_b, WhhBb, 65536);
  cast_bf16_k<<<8192, 256, 0, stream>>>(proj_W, PW, 2097152);
  bias_comb_k<<<4, 256, 0, stream>>>(bih_f, bhh_f, bih_b, bhh_b, biasF, biasB);

  // stage A: G_dir = x_chunks @ Wih_dir^T   (M=65536, N=1024, K=1024)
  // grid.x = N-blocks so consecutive blocks share the A stripe (L2 reuse)
  dim3 g1(8, 512);
  gemm_bt<true, false><<<g1, 256, 0, stream>>>(x, WihF, G, 65536, 1024, 1024, nullptr);
  gemm_bt<true, false><<<g1, 256, 0, stream>>>(x, WihB, G + 67108864, 65536, 1024, 1024, nullptr);

  // recurrent scan (both directions), writes flat [16384][2048] bf16
  lstm_scan<<<dim3(256, 2), 256, 0, stream>>>(G, WhhFb, WhhBb, biasF, biasB, flat);

  // projection: y = flat @ proj_W^T + proj_b  (M=16384, N=4096, K=2048)
  dim3 g3(32, 128);
  gemm_bt<false, true><<<g3, 256, 0, stream>>>(flat, PW, y, 16384, 4096, 2048, proj_b);

  // LayerNorm + GELU + residual
  ln_gelu_res<<<16384, 256, 0, stream>>>(y, x, ln_g, ln_b, out);
}